// Round 2
// baseline (477.649 us; speedup 1.0000x reference)
//
#include <hip/hip_runtime.h>
#include <hip/hip_bf16.h>

// Problem constants
#define T_TOK 4096   // B*S
#define DD 768
#define HH 3072
#define EE 4
#define LL 2

typedef __attribute__((ext_vector_type(8))) short short8;
typedef __attribute__((ext_vector_type(4))) float f32x4;

__device__ __forceinline__ float bf2f(ushort u) { return __uint_as_float(((unsigned)u) << 16); }
__device__ __forceinline__ ushort f2bf(float f) {
  unsigned x = __float_as_uint(f);
  return (ushort)((x + 0x7fffu + ((x >> 16) & 1u)) >> 16); // RNE
}

__device__ __forceinline__ void gl2lds16(const void* g, void* l) {
  __builtin_amdgcn_global_load_lds((const __attribute__((address_space(1))) void*)g,
                                   (__attribute__((address_space(3))) void*)l, 16, 0, 0);
}

// ---------------- prep: bucket tokens by expert, build tile table ----------------
// meta: [0..3]=offsets, [4]=total, [5]=ntiles, [6..45]=tile_expert, [46..85]=tile_mstart
__global__ __launch_bounds__(256) void prep_kernel(const int* __restrict__ eidx,
                                                   int* __restrict__ perm,
                                                   int* __restrict__ meta) {
  __shared__ int cnt[EE], cur[EE], offs[EE];
  int t = threadIdx.x;
  if (t < EE) { cnt[t] = 0; cur[t] = 0; }
  __syncthreads();
  for (int i = t; i < T_TOK; i += 256) atomicAdd(&cnt[eidx[i]], 1);
  __syncthreads();
  if (t == 0) {
    int off = 0, nt = 0;
    for (int e = 0; e < EE; e++) {
      meta[e] = off; offs[e] = off;
      int c = cnt[e];
      int n = (c + 127) >> 7;
      for (int k = 0; k < n; k++) { meta[6 + nt] = e; meta[46 + nt] = k << 7; nt++; }
      off += c;
    }
    meta[4] = off;
    meta[5] = nt;
  }
  __syncthreads();
  for (int i = t; i < T_TOK; i += 256) {
    int e = eidx[i];
    int pos = offs[e] + atomicAdd(&cur[e], 1);
    perm[pos] = i;
  }
}

// ---------------- fp32 residual init (copy) ----------------
__global__ __launch_bounds__(256) void cvt_kernel(const float* __restrict__ x,
                                                  float* __restrict__ xf, int n) {
  int i = blockIdx.x * 256 + threadIdx.x;
  int stride = gridDim.x * 256;
  for (; i < n; i += stride) xf[i] = x[i];
}

// ---------------- fp32 residual -> fp32 out ----------------
__global__ __launch_bounds__(256) void store_kernel(const float* __restrict__ xf,
                                                    float* __restrict__ out, int n) {
  int i = blockIdx.x * 256 + threadIdx.x;
  int stride = gridDim.x * 256;
  for (; i < n; i += stride) out[i] = xf[i];
}

// ---------------- LayerNorm: one wave per token, fp32 in, bf16 out ----------------
__global__ __launch_bounds__(256) void ln_kernel(const float* __restrict__ xf,
                                                 const float* __restrict__ g,
                                                 const float* __restrict__ b,
                                                 ushort* __restrict__ h) {
  int wid = blockIdx.x * 4 + (threadIdx.x >> 6);
  int lane = threadIdx.x & 63;
  const float* xr = xf + (size_t)wid * DD;
  float v[12], s = 0.f, ss = 0.f;
#pragma unroll
  for (int i = 0; i < 12; i++) {
    v[i] = xr[lane + i * 64];
    s += v[i]; ss += v[i] * v[i];
  }
#pragma unroll
  for (int o = 32; o; o >>= 1) { s += __shfl_xor(s, o, 64); ss += __shfl_xor(ss, o, 64); }
  float mu = s * (1.f / DD);
  float var = ss * (1.f / DD) - mu * mu;
  float rs = rsqrtf(var + 1e-6f);
  ushort* hr = h + (size_t)wid * DD;
#pragma unroll
  for (int i = 0; i < 12; i++) {
    int c = lane + i * 64;
    hr[c] = f2bf((v[i] - mu) * rs * g[c] + b[c]);
  }
}

// ---------------- fp32 (R,C) -> bf16 (C,R) transpose+downcast, batched over z ----------------
__global__ __launch_bounds__(256) void transpose_f32_bf16(const float* __restrict__ src,
                                                          ushort* __restrict__ dst,
                                                          int R, int C) {
  __shared__ ushort tile[64][68];
  size_t mo = (size_t)blockIdx.z * R * C;
  src += mo;
  dst += mo;
  int c0 = blockIdx.x * 64, r0 = blockIdx.y * 64;
  int t = threadIdx.x;
  int tr = t >> 4;          // 0..15
  int tc = (t & 15) << 2;   // 0..60 step 4
#pragma unroll
  for (int i = 0; i < 4; i++) {
    int r = tr + i * 16;
    float4 v = *(const float4*)(src + (size_t)(r0 + r) * C + (c0 + tc));
    tile[r][tc] = f2bf(v.x); tile[r][tc + 1] = f2bf(v.y);
    tile[r][tc + 2] = f2bf(v.z); tile[r][tc + 3] = f2bf(v.w);
  }
  __syncthreads();
#pragma unroll
  for (int i = 0; i < 4; i++) {
    int c = tr + i * 16;
    ushort4 v;
    v.x = tile[tc][c]; v.y = tile[tc + 1][c]; v.z = tile[tc + 2][c]; v.w = tile[tc + 3][c];
    *(ushort4*)(dst + (size_t)(c0 + c) * R + (r0 + tc)) = v;
  }
}

// ---------------- grouped GEMM, m97 structure ----------------
// A: (T_TOK, K) bf16, rows gathered via perm.  Bt: (E*NTOT, K) bf16 (pre-transposed).
// GELU=true : C = gelu(A@B + bias) -> bf16 a (T_TOK, HH)
// GELU=false: xf[token] += A@B + bias (fp32 accumulate), NTOT = DD
template <int K, int NTOT, bool GELU>
__global__ __launch_bounds__(256) void gemm_kernel(const ushort* __restrict__ A,
                                                   const ushort* __restrict__ Bt,
                                                   const float* __restrict__ bias,
                                                   void* __restrict__ Cout,
                                                   const int* __restrict__ perm,
                                                   const int* __restrict__ meta) {
  int ty = blockIdx.y;
  if (ty >= meta[5]) return;
  int e = meta[6 + ty];
  int mstart = meta[46 + ty];
  int off0 = meta[e];
  int cnt = meta[e + 1] - off0;
  int ntile = blockIdx.x;

  __shared__ __align__(16) ushort As[128 * 32];
  __shared__ __align__(16) ushort Bs[128 * 32];

  int tid = threadIdx.x;
  int w = tid >> 6, lane = tid & 63;

  // staging assignment: wave w stages rows [w*32, w*32+32) of each 128x32 tile
  int r0 = w * 32 + (lane >> 2);
  int r1 = r0 + 16;
  int koff = (lane & 3) * 8; // element offset (16B lanes-quad)

  int tok0 = perm[off0 + min(mstart + r0, cnt - 1)];
  int tok1 = perm[off0 + min(mstart + r1, cnt - 1)];
  const ushort* ag0 = A + (size_t)tok0 * K + koff;
  const ushort* ag1 = A + (size_t)tok1 * K + koff;
  const ushort* bg0 = Bt + ((size_t)e * NTOT + ntile * 128 + r0) * K + koff;
  const ushort* bg1 = bg0 + (size_t)16 * K;
  ushort* al0 = As + r0 * 32 + koff;
  ushort* al1 = As + r1 * 32 + koff;
  ushort* bl0 = Bs + r0 * 32 + koff;
  ushort* bl1 = Bs + r1 * 32 + koff;

  int wm = (w >> 1) * 64, wn = (w & 1) * 64;
  int qm = lane & 15;
  int qk = (lane >> 4) * 8;

  f32x4 acc[4][4];
#pragma unroll
  for (int mi = 0; mi < 4; mi++)
#pragma unroll
    for (int ni = 0; ni < 4; ni++) acc[mi][ni] = (f32x4){0.f, 0.f, 0.f, 0.f};

  for (int k0 = 0; k0 < K; k0 += 32) {
    gl2lds16(ag0 + k0, al0);
    gl2lds16(ag1 + k0, al1);
    gl2lds16(bg0 + k0, bl0);
    gl2lds16(bg1 + k0, bl1);
    __syncthreads();
    short8 af[4], bfr[4];
#pragma unroll
    for (int mi = 0; mi < 4; mi++)
      af[mi] = *(const short8*)(As + (wm + mi * 16 + qm) * 32 + qk);
#pragma unroll
    for (int ni = 0; ni < 4; ni++)
      bfr[ni] = *(const short8*)(Bs + (wn + ni * 16 + qm) * 32 + qk);
#pragma unroll
    for (int mi = 0; mi < 4; mi++)
#pragma unroll
      for (int ni = 0; ni < 4; ni++)
        acc[mi][ni] = __builtin_amdgcn_mfma_f32_16x16x32_bf16(af[mi], bfr[ni], acc[mi][ni], 0, 0, 0);
    __syncthreads();
  }

  // epilogue. C/D mapping: col = lane&15, row = (lane>>4)*4 + reg
  int col[4];
  float bv[4];
#pragma unroll
  for (int ni = 0; ni < 4; ni++) {
    col[ni] = ntile * 128 + wn + ni * 16 + qm;
    bv[ni] = bias[e * NTOT + col[ni]];
  }
  int rbase = (lane >> 4) * 4;
#pragma unroll
  for (int mi = 0; mi < 4; mi++) {
#pragma unroll
    for (int r = 0; r < 4; r++) {
      int mg = mstart + wm + mi * 16 + rbase + r;
      if (mg >= cnt) continue;
      int token = perm[off0 + mg];
      if (GELU) {
        ushort* crow = (ushort*)Cout + (size_t)token * HH;
#pragma unroll
        for (int ni = 0; ni < 4; ni++) {
          float vv = acc[mi][ni][r] + bv[ni];
          vv = 0.5f * vv * (1.f + erff(vv * 0.70710678118f));
          crow[col[ni]] = f2bf(vv);
        }
      } else {
        float* crow = (float*)Cout + (size_t)token * DD;
#pragma unroll
        for (int ni = 0; ni < 4; ni++) crow[col[ni]] += acc[mi][ni][r] + bv[ni];
      }
    }
  }
}

// ---------------- host ----------------
extern "C" void kernel_launch(void* const* d_in, const int* in_sizes, int n_in,
                              void* d_out, int out_size, void* d_ws, size_t ws_size,
                              hipStream_t stream) {
  const float* x   = (const float*)d_in[0];
  const int*   eidx = (const int*)d_in[1];
  const float* W1  = (const float*)d_in[2];
  const float* b1  = (const float*)d_in[3];
  const float* W2  = (const float*)d_in[4];
  const float* b2  = (const float*)d_in[5];
  const float* lng = (const float*)d_in[6];
  const float* lnb = (const float*)d_in[7];

  char* ws = (char*)d_ws;
  // layout (bytes): xf fp32 12582912 | h bf16 6291456 | a bf16 25165824 | Wt bf16 18874368 | perm | meta
  float*  xf   = (float*)(ws + 0);
  ushort* h    = (ushort*)(ws + 12582912);
  ushort* a    = (ushort*)(ws + 18874368);
  ushort* Wt   = (ushort*)(ws + 44040192);
  int*    perm = (int*)(ws + 62914560);
  int*    meta = (int*)(ws + 62930944);

  const int NELT = T_TOK * DD; // 3145728

  prep_kernel<<<1, 256, 0, stream>>>(eidx, perm, meta);
  cvt_kernel<<<3072, 256, 0, stream>>>(x, xf, NELT);

  for (int l = 0; l < LL; l++) {
    ln_kernel<<<T_TOK / 4, 256, 0, stream>>>(xf, lng + l * DD, lnb + l * DD, h);
    // W1 slice (E, D, H) fp32 -> Wt (E, H, D) bf16
    transpose_f32_bf16<<<dim3(HH / 64, DD / 64, EE), 256, 0, stream>>>(
        W1 + (size_t)l * EE * DD * HH, Wt, DD, HH);
    gemm_kernel<DD, HH, true><<<dim3(HH / 128, 36), 256, 0, stream>>>(
        h, Wt, b1 + l * EE * HH, (void*)a, perm, meta);
    // W2 slice (E, H, D) fp32 -> Wt (E, D, H) bf16
    transpose_f32_bf16<<<dim3(DD / 64, HH / 64, EE), 256, 0, stream>>>(
        W2 + (size_t)l * EE * HH * DD, Wt, HH, DD);
    gemm_kernel<HH, DD, false><<<dim3(DD / 128, 36), 256, 0, stream>>>(
        a, Wt, b2 + l * EE * DD, (void*)xf, perm, meta);
  }

  store_kernel<<<3072, 256, 0, stream>>>(xf, (float*)d_out, NELT);
}

// Round 3
// 440.636 us; speedup vs baseline: 1.0840x; 1.0840x over previous
//
#include <hip/hip_runtime.h>
#include <hip/hip_bf16.h>

// Problem constants
#define T_TOK 4096   // B*S
#define DD 768
#define HH 3072
#define EE 4
#define LL 2

typedef __attribute__((ext_vector_type(8))) short short8;
typedef __attribute__((ext_vector_type(4))) float f32x4;

__device__ __forceinline__ float bf2f(ushort u) { return __uint_as_float(((unsigned)u) << 16); }
__device__ __forceinline__ ushort f2bf(float f) {
  unsigned x = __float_as_uint(f);
  return (ushort)((x + 0x7fffu + ((x >> 16) & 1u)) >> 16); // RNE
}

__device__ __forceinline__ void gl2lds16(const void* g, void* l) {
  __builtin_amdgcn_global_load_lds((const __attribute__((address_space(1))) void*)g,
                                   (__attribute__((address_space(3))) void*)l, 16, 0, 0);
}

// ---------------- prep: bucket tokens by expert, build tile table ----------------
// meta: [0..3]=offsets, [4]=total, [5]=ntiles, [6..45]=tile_expert, [46..85]=tile_mstart
__global__ __launch_bounds__(256) void prep_kernel(const int* __restrict__ eidx,
                                                   int* __restrict__ perm,
                                                   int* __restrict__ inv,
                                                   int* __restrict__ meta) {
  __shared__ int cnt[EE], cur[EE], offs[EE];
  int t = threadIdx.x;
  if (t < EE) { cnt[t] = 0; cur[t] = 0; }
  __syncthreads();
  for (int i = t; i < T_TOK; i += 256) atomicAdd(&cnt[eidx[i]], 1);
  __syncthreads();
  if (t == 0) {
    int off = 0, nt = 0;
    for (int e = 0; e < EE; e++) {
      meta[e] = off; offs[e] = off;
      int c = cnt[e];
      int n = (c + 127) >> 7;
      for (int k = 0; k < n; k++) { meta[6 + nt] = e; meta[46 + nt] = k << 7; nt++; }
      off += c;
    }
    meta[4] = off;
    meta[5] = nt;
  }
  __syncthreads();
  for (int i = t; i < T_TOK; i += 256) {
    int e = eidx[i];
    int pos = offs[e] + atomicAdd(&cur[e], 1);
    perm[pos] = i;
    inv[i] = pos;
  }
}

// ---------------- fp32 residual init (copy) ----------------
__global__ __launch_bounds__(256) void cvt_kernel(const float* __restrict__ x,
                                                  float* __restrict__ xf, int n) {
  int i = blockIdx.x * 256 + threadIdx.x;
  int stride = gridDim.x * 256;
  for (; i < n; i += stride) xf[i] = x[i];
}

// ---------------- fp32 residual -> fp32 out ----------------
__global__ __launch_bounds__(256) void store_kernel(const float* __restrict__ xf,
                                                    float* __restrict__ out, int n) {
  int i = blockIdx.x * 256 + threadIdx.x;
  int stride = gridDim.x * 256;
  for (; i < n; i += stride) out[i] = xf[i];
}

// ---------------- LayerNorm: one wave per token, fp32 in, bf16 out (PERMUTED) ----------------
__global__ __launch_bounds__(256) void ln_kernel(const float* __restrict__ xf,
                                                 const float* __restrict__ g,
                                                 const float* __restrict__ b,
                                                 const int* __restrict__ inv,
                                                 ushort* __restrict__ h) {
  int wid = blockIdx.x * 4 + (threadIdx.x >> 6);
  int lane = threadIdx.x & 63;
  const float* xr = xf + (size_t)wid * DD;
  float v[12], s = 0.f, ss = 0.f;
#pragma unroll
  for (int i = 0; i < 12; i++) {
    v[i] = xr[lane + i * 64];
    s += v[i]; ss += v[i] * v[i];
  }
#pragma unroll
  for (int o = 32; o; o >>= 1) { s += __shfl_xor(s, o, 64); ss += __shfl_xor(ss, o, 64); }
  float mu = s * (1.f / DD);
  float var = ss * (1.f / DD) - mu * mu;
  float rs = rsqrtf(var + 1e-6f);
  ushort* hr = h + (size_t)inv[wid] * DD;
#pragma unroll
  for (int i = 0; i < 12; i++) {
    int c = lane + i * 64;
    hr[c] = f2bf((v[i] - mu) * rs * g[c] + b[c]);
  }
}

// ---------------- fp32 (R,C) -> bf16 (C,R) transpose+downcast, batched over z ----------------
__global__ __launch_bounds__(256) void transpose_f32_bf16(const float* __restrict__ src,
                                                          ushort* __restrict__ dst,
                                                          int R, int C) {
  __shared__ ushort tile[64][68];
  size_t mo = (size_t)blockIdx.z * R * C;
  src += mo;
  dst += mo;
  int c0 = blockIdx.x * 64, r0 = blockIdx.y * 64;
  int t = threadIdx.x;
  int tr = t >> 4;          // 0..15
  int tc = (t & 15) << 2;   // 0..60 step 4
#pragma unroll
  for (int i = 0; i < 4; i++) {
    int r = tr + i * 16;
    float4 v = *(const float4*)(src + (size_t)(r0 + r) * C + (c0 + tc));
    tile[r][tc] = f2bf(v.x); tile[r][tc + 1] = f2bf(v.y);
    tile[r][tc + 2] = f2bf(v.z); tile[r][tc + 3] = f2bf(v.w);
  }
  __syncthreads();
#pragma unroll
  for (int i = 0; i < 4; i++) {
    int c = tr + i * 16;
    ushort4 v;
    v.x = tile[tc][c]; v.y = tile[tc + 1][c]; v.z = tile[tc + 2][c]; v.w = tile[tc + 3][c];
    *(ushort4*)(dst + (size_t)(c0 + c) * R + (r0 + tc)) = v;
  }
}

// ---------------- grouped GEMM, BK=64, permuted A ----------------
// A: (T_TOK, KTOT) bf16 in PERMUTED row order (contiguous per expert).
// Bt: (E*NTOT, KTOT) bf16.  K range handled: [blockIdx.z*KLEN, +KLEN)
// GELU=true : a_perm[pos] = gelu(A@B + bias) bf16, coalesced via LDS repack
// GELU=false: xf[token] += A@B (+bias on split 0) via fp32 atomicAdd
template <int KTOT, int KLEN, int NTOT, bool GELU>
__global__ __launch_bounds__(256) void gemm_kernel(const ushort* __restrict__ A,
                                                   const ushort* __restrict__ Bt,
                                                   const float* __restrict__ bias,
                                                   void* __restrict__ Cout,
                                                   const int* __restrict__ perm,
                                                   const int* __restrict__ meta) {
  int ty = blockIdx.y;
  if (ty >= meta[5]) return;
  int e = meta[6 + ty];
  int mstart = meta[46 + ty];
  int off0 = meta[e];
  int cnt = meta[e + 1] - off0;
  if (cnt <= 0) return;
  int ntile = blockIdx.x;
  int kbegin = blockIdx.z * KLEN;

  // 32 KB LDS: staging As(16K)+Bs(16K); epilogue repack reuses all 32K as 128x128 bf16
  __shared__ __align__(16) ushort lds[16384];
  ushort* As = lds;          // 128 rows x 64 k
  ushort* Bs = lds + 8192;   // 128 rows x 64 k

  int tid = threadIdx.x;
  int w = tid >> 6, lane = tid & 63;

  // staging: instruction i (0..3) covers rows [w*32 + i*8, +8); lane>>3 row-in-group,
  // (lane&7)*8 k-elements (16B). LDS addr = wave_base + lane*16 (wave-uniform + lane*16).
  int rr = lane >> 3;           // 0..7
  int koff = (lane & 7) * 8;    // element offset
  const ushort* agp[4];
  const ushort* bgp[4];
  ushort* alp[4];
  ushort* blp[4];
#pragma unroll
  for (int i = 0; i < 4; i++) {
    int r = w * 32 + i * 8 + rr;
    int arow = off0 + min(mstart + r, cnt - 1);
    int brow = e * NTOT + ntile * 128 + r;
    agp[i] = A + (size_t)arow * KTOT + kbegin + koff;
    bgp[i] = Bt + (size_t)brow * KTOT + kbegin + koff;
    alp[i] = As + r * 64 + koff;
    blp[i] = Bs + r * 64 + koff;
  }

  int wm = (w >> 1) * 64, wn = (w & 1) * 64;
  int qm = lane & 15;
  int qk = (lane >> 4) * 8;

  f32x4 acc[4][4];
#pragma unroll
  for (int mi = 0; mi < 4; mi++)
#pragma unroll
    for (int ni = 0; ni < 4; ni++) acc[mi][ni] = (f32x4){0.f, 0.f, 0.f, 0.f};

  for (int k0 = 0; k0 < KLEN; k0 += 64) {
#pragma unroll
    for (int i = 0; i < 4; i++) {
      gl2lds16(agp[i] + k0, alp[i]);
      gl2lds16(bgp[i] + k0, blp[i]);
    }
    __syncthreads();
#pragma unroll
    for (int h2 = 0; h2 < 2; h2++) {
      short8 af[4], bfr[4];
#pragma unroll
      for (int mi = 0; mi < 4; mi++)
        af[mi] = *(const short8*)(As + (wm + mi * 16 + qm) * 64 + h2 * 32 + qk);
#pragma unroll
      for (int ni = 0; ni < 4; ni++)
        bfr[ni] = *(const short8*)(Bs + (wn + ni * 16 + qm) * 64 + h2 * 32 + qk);
#pragma unroll
      for (int mi = 0; mi < 4; mi++)
#pragma unroll
        for (int ni = 0; ni < 4; ni++)
          acc[mi][ni] = __builtin_amdgcn_mfma_f32_16x16x32_bf16(af[mi], bfr[ni], acc[mi][ni], 0, 0, 0);
    }
    __syncthreads();
  }

  // epilogue. C/D mapping: col = lane&15, row = (lane>>4)*4 + reg
  int rbase = (lane >> 4) * 4;
  if (GELU) {
    // bias + gelu -> LDS 128x128 bf16 repack -> coalesced row stores (permuted space)
    float bv[4];
#pragma unroll
    for (int ni = 0; ni < 4; ni++)
      bv[ni] = bias[e * NTOT + ntile * 128 + wn + ni * 16 + qm];
#pragma unroll
    for (int mi = 0; mi < 4; mi++)
#pragma unroll
      for (int ni = 0; ni < 4; ni++) {
        int c = wn + ni * 16 + qm;
#pragma unroll
        for (int r = 0; r < 4; r++) {
          float vv = acc[mi][ni][r] + bv[ni];
          vv = 0.5f * vv * (1.f + erff(vv * 0.70710678118f));
          lds[(wm + mi * 16 + rbase + r) * 128 + c] = f2bf(vv);
        }
      }
    __syncthreads();
    int row0 = tid >> 4;            // 0..15
    int cseg = (tid & 15) * 8;      // col elements, 16B chunks
    ushort* aout = (ushort*)Cout;
#pragma unroll
    for (int it = 0; it < 8; it++) {
      int row = it * 16 + row0;
      int mg = mstart + row;
      if (mg < cnt) {
        short8 v = *(const short8*)(lds + row * 128 + cseg);
        *(short8*)(aout + (size_t)(off0 + mg) * HH + ntile * 128 + cseg) = v;
      }
    }
  } else {
    // atomic fp32 accumulate into residual xf[token]; bias only on split 0
    float* xf = (float*)Cout;
    float bv[4];
#pragma unroll
    for (int ni = 0; ni < 4; ni++)
      bv[ni] = (blockIdx.z == 0) ? bias[e * NTOT + ntile * 128 + wn + ni * 16 + qm] : 0.f;
#pragma unroll
    for (int mi = 0; mi < 4; mi++) {
#pragma unroll
      for (int r = 0; r < 4; r++) {
        int mg = mstart + wm + mi * 16 + rbase + r;
        if (mg >= cnt) continue;
        int token = perm[off0 + mg];
        float* crow = xf + (size_t)token * DD + ntile * 128;
#pragma unroll
        for (int ni = 0; ni < 4; ni++)
          atomicAdd(&crow[wn + ni * 16 + qm], acc[mi][ni][r] + bv[ni]);
      }
    }
  }
}

// ---------------- host ----------------
extern "C" void kernel_launch(void* const* d_in, const int* in_sizes, int n_in,
                              void* d_out, int out_size, void* d_ws, size_t ws_size,
                              hipStream_t stream) {
  const float* x   = (const float*)d_in[0];
  const int*   eidx = (const int*)d_in[1];
  const float* W1  = (const float*)d_in[2];
  const float* b1  = (const float*)d_in[3];
  const float* W2  = (const float*)d_in[4];
  const float* b2  = (const float*)d_in[5];
  const float* lng = (const float*)d_in[6];
  const float* lnb = (const float*)d_in[7];

  char* ws = (char*)d_ws;
  // layout (bytes): xf fp32 12582912 | h bf16 6291456 | a bf16 25165824 | Wt bf16 18874368 | perm | inv | meta
  float*  xf   = (float*)(ws + 0);
  ushort* h    = (ushort*)(ws + 12582912);
  ushort* a    = (ushort*)(ws + 18874368);
  ushort* Wt   = (ushort*)(ws + 44040192);
  int*    perm = (int*)(ws + 62914560);
  int*    inv  = (int*)(ws + 62930944);
  int*    meta = (int*)(ws + 62947328);

  const int NELT = T_TOK * DD; // 3145728

  prep_kernel<<<1, 256, 0, stream>>>(eidx, perm, inv, meta);
  cvt_kernel<<<3072, 256, 0, stream>>>(x, xf, NELT);

  for (int l = 0; l < LL; l++) {
    ln_kernel<<<T_TOK / 4, 256, 0, stream>>>(xf, lng + l * DD, lnb + l * DD, inv, h);
    // W1 slice (E, D, H) fp32 -> Wt (E, H, D) bf16
    transpose_f32_bf16<<<dim3(HH / 64, DD / 64, EE), 256, 0, stream>>>(
        W1 + (size_t)l * EE * DD * HH, Wt, DD, HH);
    gemm_kernel<DD, DD, HH, true><<<dim3(HH / 128, 36), 256, 0, stream>>>(
        h, Wt, b1 + l * EE * HH, (void*)a, perm, meta);
    // W2 slice (E, H, D) fp32 -> Wt (E, D, H) bf16
    transpose_f32_bf16<<<dim3(DD / 64, HH / 64, EE), 256, 0, stream>>>(
        W2 + (size_t)l * EE * HH * DD, Wt, HH, DD);
    gemm_kernel<HH, HH / 2, DD, false><<<dim3(DD / 128, 36, 2), 256, 0, stream>>>(
        a, Wt, b2 + l * EE * DD, (void*)xf, perm, meta);
  }

  store_kernel<<<3072, 256, 0, stream>>>(xf, (float*)d_out, NELT);
}

// Round 4
// 392.428 us; speedup vs baseline: 1.2172x; 1.1228x over previous
//
#include <hip/hip_runtime.h>
#include <hip/hip_bf16.h>

// Problem constants
#define T_TOK 4096   // B*S
#define DD 768
#define HH 3072
#define EE 4
#define LL 2
#define NELT (T_TOK * DD)

typedef __attribute__((ext_vector_type(8))) short short8;
typedef __attribute__((ext_vector_type(4))) float f32x4;

__device__ __forceinline__ float bf2f(ushort u) { return __uint_as_float(((unsigned)u) << 16); }
__device__ __forceinline__ ushort f2bf(float f) {
  unsigned x = __float_as_uint(f);
  return (ushort)((x + 0x7fffu + ((x >> 16) & 1u)) >> 16); // RNE
}

__device__ __forceinline__ void gl2lds16(const void* g, void* l) {
  __builtin_amdgcn_global_load_lds((const __attribute__((address_space(1))) void*)g,
                                   (__attribute__((address_space(3))) void*)l, 16, 0, 0);
}

// ---------------- prep: bucket tokens by expert, 64-row tiles ----------------
// meta: [0..3]=expert offsets, [4]=total, [5]=ntiles, [8+t]=tile_expert, [96+t]=tile_mstart
__global__ __launch_bounds__(256) void prep_kernel(const int* __restrict__ eidx,
                                                   int* __restrict__ inv,
                                                   int* __restrict__ meta) {
  __shared__ int cnt[EE], cur[EE], offs[EE];
  int t = threadIdx.x;
  if (t < EE) { cnt[t] = 0; cur[t] = 0; }
  __syncthreads();
  for (int i = t; i < T_TOK; i += 256) atomicAdd(&cnt[eidx[i]], 1);
  __syncthreads();
  if (t == 0) {
    int off = 0, nt = 0;
    for (int e = 0; e < EE; e++) {
      meta[e] = off; offs[e] = off;
      int c = cnt[e];
      int n = (c + 63) >> 6;
      for (int k = 0; k < n; k++) { meta[8 + nt] = e; meta[96 + nt] = k << 6; nt++; }
      off += c;
    }
    meta[4] = off;
    meta[5] = nt;
  }
  __syncthreads();
  for (int i = t; i < T_TOK; i += 256) {
    int e = eidx[i];
    inv[i] = offs[e] + atomicAdd(&cur[e], 1);
  }
}

// ---------------- LayerNorm (wave/token), optional fused residual partial-sum ----------------
// HASY: v = x[tok] + y0[pos] + y1[pos];  WRITEX: xf[tok] = v.  Writes h[pos] = LN(v).
template <bool HASY, bool WRITEX>
__global__ __launch_bounds__(256) void ln_kernel(const float* __restrict__ x,
                                                 const float* __restrict__ y,
                                                 const float* __restrict__ g,
                                                 const float* __restrict__ b,
                                                 const int* __restrict__ inv,
                                                 ushort* __restrict__ h,
                                                 float* __restrict__ xf) {
  int wid = blockIdx.x * 4 + (threadIdx.x >> 6);
  int lane = threadIdx.x & 63;
  int pos = inv[wid];
  const float* xr = x + (size_t)wid * DD;
  const float* y0 = y + (size_t)pos * DD;
  const float* y1 = y0 + NELT;
  float v[12], s = 0.f, ss = 0.f;
#pragma unroll
  for (int i = 0; i < 12; i++) {
    int c = lane + i * 64;
    float vv = xr[c];
    if (HASY) vv += y0[c] + y1[c];
    if (WRITEX) xf[(size_t)wid * DD + c] = vv;
    v[i] = vv;
    s += vv; ss += vv * vv;
  }
#pragma unroll
  for (int o = 32; o; o >>= 1) { s += __shfl_xor(s, o, 64); ss += __shfl_xor(ss, o, 64); }
  float mu = s * (1.f / DD);
  float var = ss * (1.f / DD) - mu * mu;
  float rs = rsqrtf(var + 1e-6f);
  ushort* hr = h + (size_t)pos * DD;
#pragma unroll
  for (int i = 0; i < 12; i++) {
    int c = lane + i * 64;
    hr[c] = f2bf((v[i] - mu) * rs * g[c] + b[c]);
  }
}

// ---------------- final: out = xf + y0 + y1 (wave/token) ----------------
__global__ __launch_bounds__(256) void store_kernel(const float* __restrict__ xf,
                                                    const float* __restrict__ y,
                                                    const int* __restrict__ inv,
                                                    float* __restrict__ out) {
  int wid = blockIdx.x * 4 + (threadIdx.x >> 6);
  int lane = threadIdx.x & 63;
  int pos = inv[wid];
  const float* xr = xf + (size_t)wid * DD;
  const float* y0 = y + (size_t)pos * DD;
  const float* y1 = y0 + NELT;
  float* o = out + (size_t)wid * DD;
#pragma unroll
  for (int i = 0; i < 12; i++) {
    int c = lane + i * 64;
    o[c] = xr[c] + y0[c] + y1[c];
  }
}

// ---------------- fp32 (R,C) -> bf16 (C,R) transpose+downcast, batched over z ----------------
__global__ __launch_bounds__(256) void transpose_f32_bf16(const float* __restrict__ src,
                                                          ushort* __restrict__ dst,
                                                          int R, int C) {
  __shared__ ushort tile[64][68];
  size_t mo = (size_t)blockIdx.z * R * C;
  src += mo;
  dst += mo;
  int c0 = blockIdx.x * 64, r0 = blockIdx.y * 64;
  int t = threadIdx.x;
  int tr = t >> 4;          // 0..15
  int tc = (t & 15) << 2;   // 0..60 step 4
#pragma unroll
  for (int i = 0; i < 4; i++) {
    int r = tr + i * 16;
    float4 v = *(const float4*)(src + (size_t)(r0 + r) * C + (c0 + tc));
    tile[r][tc] = f2bf(v.x); tile[r][tc + 1] = f2bf(v.y);
    tile[r][tc + 2] = f2bf(v.z); tile[r][tc + 3] = f2bf(v.w);
  }
  __syncthreads();
#pragma unroll
  for (int i = 0; i < 4; i++) {
    int c = tr + i * 16;
    ushort4 v;
    v.x = tile[tc][c]; v.y = tile[tc + 1][c]; v.z = tile[tc + 2][c]; v.w = tile[tc + 3][c];
    *(ushort4*)(dst + (size_t)(c0 + c) * R + (r0 + tc)) = v;
  }
}

// ---------------- grouped GEMM, 64M x 128N tile, BK=64, XOR-swizzled LDS ----------------
// A: (T_TOK, KTOT) bf16 PERMUTED rows.  Bt: (E*NTOT, KTOT) bf16.
// GELU=true : a[pos] = gelu(A@B + bias) bf16 (LDS repack, coalesced)
// GELU=false: partial fp32 y[z*NELT + pos*DD + n] = A@B (+bias on split 0), coalesced
template <int KTOT, int KLEN, int NTOT, bool GELU>
__global__ __launch_bounds__(256, 4) void gemm_kernel(const ushort* __restrict__ A,
                                                      const ushort* __restrict__ Bt,
                                                      const float* __restrict__ bias,
                                                      void* __restrict__ Cout,
                                                      const int* __restrict__ meta) {
  int ty = blockIdx.y;
  if (ty >= meta[5]) return;
  int e = meta[8 + ty];
  int mstart = meta[96 + ty];
  int off0 = meta[e];
  int cnt = meta[e + 1] - off0;
  int ntile = blockIdx.x;
  int z = blockIdx.z;
  int kbegin = z * KLEN;

  // 24 KB LDS: As 64x64, Bs 128x64 (bf16). Epilogue repack reuses first 16 KB.
  __shared__ __align__(16) ushort lds[12288];
  ushort* As = lds;          // 64 rows x 64 k
  ushort* Bs = lds + 4096;   // 128 rows x 64 k

  int tid = threadIdx.x;
  int w = tid >> 6, lane = tid & 63;

  // staging: row-group rr = lane>>3 (0..7); global chunk = (lane&7) ^ rr (XOR swizzle)
  // so LDS[r][c] holds global chunk (c ^ (r&7)). LDS dest = uniform base + lane*16.
  int rr = lane >> 3;
  int swz = ((lane & 7) ^ rr) * 8; // element offset of the 16B chunk this lane fetches
  const ushort* agp[2];
  const ushort* bgp[4];
  ushort* alp[2];
  ushort* blp[4];
#pragma unroll
  for (int i = 0; i < 2; i++) {
    int r = w * 16 + i * 8;                       // uniform part of A row
    int arow = off0 + min(mstart + r + rr, cnt - 1);
    agp[i] = A + (size_t)arow * KTOT + kbegin + swz;
    alp[i] = As + r * 64 + lane * 8;              // = uniform + lane*16B
  }
#pragma unroll
  for (int i = 0; i < 4; i++) {
    int r = w * 32 + i * 8;
    int brow = e * NTOT + ntile * 128 + r + rr;
    bgp[i] = Bt + (size_t)brow * KTOT + kbegin + swz;
    blp[i] = Bs + r * 64 + lane * 8;
  }

  int wm = (w >> 1) * 32, wn = (w & 1) * 64;
  int qm = lane & 15;
  int quad = lane >> 4;
  int s7 = qm & 7;

  f32x4 acc[2][4];
#pragma unroll
  for (int mi = 0; mi < 2; mi++)
#pragma unroll
    for (int ni = 0; ni < 4; ni++) acc[mi][ni] = (f32x4){0.f, 0.f, 0.f, 0.f};

  for (int k0 = 0; k0 < KLEN; k0 += 64) {
#pragma unroll
    for (int i = 0; i < 2; i++) gl2lds16(agp[i] + k0, alp[i]);
#pragma unroll
    for (int i = 0; i < 4; i++) gl2lds16(bgp[i] + k0, blp[i]);
    __syncthreads();
#pragma unroll
    for (int h2 = 0; h2 < 2; h2++) {
      int lchunk = ((h2 * 4 + quad) ^ s7) * 8;    // un-swizzle
      short8 af[2], bfr[4];
#pragma unroll
      for (int mi = 0; mi < 2; mi++)
        af[mi] = *(const short8*)(As + (wm + mi * 16 + qm) * 64 + lchunk);
#pragma unroll
      for (int ni = 0; ni < 4; ni++)
        bfr[ni] = *(const short8*)(Bs + (wn + ni * 16 + qm) * 64 + lchunk);
#pragma unroll
      for (int mi = 0; mi < 2; mi++)
#pragma unroll
        for (int ni = 0; ni < 4; ni++)
          acc[mi][ni] = __builtin_amdgcn_mfma_f32_16x16x32_bf16(af[mi], bfr[ni], acc[mi][ni], 0, 0, 0);
    }
    __syncthreads();
  }

  // epilogue. C/D mapping: col = lane&15, row = quad*4 + reg
  int rbase = quad * 4;
  float bv[4];
#pragma unroll
  for (int ni = 0; ni < 4; ni++)
    bv[ni] = (!GELU && z != 0) ? 0.f : bias[e * NTOT + ntile * 128 + wn + ni * 16 + qm];

  if (GELU) {
    // bias+gelu -> LDS 64x128 bf16 -> coalesced 16B row stores (permuted space)
#pragma unroll
    for (int mi = 0; mi < 2; mi++)
#pragma unroll
      for (int ni = 0; ni < 4; ni++) {
        int c = wn + ni * 16 + qm;
#pragma unroll
        for (int r = 0; r < 4; r++) {
          float vv = acc[mi][ni][r] + bv[ni];
          vv = 0.5f * vv * (1.f + erff(vv * 0.70710678118f));
          lds[(wm + mi * 16 + rbase + r) * 128 + c] = f2bf(vv);
        }
      }
    __syncthreads();
    int row0 = tid >> 4;            // 0..15
    int cseg = (tid & 15) * 8;      // 16B chunks
    ushort* aout = (ushort*)Cout;
#pragma unroll
    for (int it = 0; it < 4; it++) {
      int row = it * 16 + row0;
      int mg = mstart + row;
      if (mg < cnt) {
        short8 v = *(const short8*)(lds + row * 128 + cseg);
        *(short8*)(aout + (size_t)(off0 + mg) * HH + ntile * 128 + cseg) = v;
      }
    }
  } else {
    // coalesced fp32 partial stores (permuted space), no atomics
    float* y = (float*)Cout + (size_t)z * NELT;
#pragma unroll
    for (int mi = 0; mi < 2; mi++) {
#pragma unroll
      for (int r = 0; r < 4; r++) {
        int mg = mstart + wm + mi * 16 + rbase + r;
        if (mg >= cnt) continue;
        float* crow = y + (size_t)(off0 + mg) * DD + ntile * 128;
#pragma unroll
        for (int ni = 0; ni < 4; ni++)
          crow[wn + ni * 16 + qm] = acc[mi][ni][r] + bv[ni];
      }
    }
  }
}

// ---------------- host ----------------
extern "C" void kernel_launch(void* const* d_in, const int* in_sizes, int n_in,
                              void* d_out, int out_size, void* d_ws, size_t ws_size,
                              hipStream_t stream) {
  const float* x   = (const float*)d_in[0];
  const int*  eidx = (const int*)d_in[1];
  const float* W1  = (const float*)d_in[2];
  const float* b1  = (const float*)d_in[3];
  const float* W2  = (const float*)d_in[4];
  const float* b2  = (const float*)d_in[5];
  const float* lng = (const float*)d_in[6];
  const float* lnb = (const float*)d_in[7];

  char* ws = (char*)d_ws;
  // layout (bytes): xf 12582912 | h 6291456 | a 25165824 | Wt 18874368 | y 25165824 | inv | meta
  float*  xf   = (float*)(ws + 0);
  ushort* h    = (ushort*)(ws + 12582912);
  ushort* a    = (ushort*)(ws + 18874368);
  ushort* Wt   = (ushort*)(ws + 44040192);
  float*  y    = (float*)(ws + 62914560);
  int*    inv  = (int*)(ws + 88080384);
  int*    meta = (int*)(ws + 88096768);

  prep_kernel<<<1, 256, 0, stream>>>(eidx, inv, meta);

  for (int l = 0; l < LL; l++) {
    if (l == 0)
      ln_kernel<false, false><<<T_TOK / 4, 256, 0, stream>>>(
          x, y, lng, lnb, inv, h, xf);
    else
      ln_kernel<true, true><<<T_TOK / 4, 256, 0, stream>>>(
          x, y, lng + l * DD, lnb + l * DD, inv, h, xf);
    // W1 slice (E, D, H) fp32 -> Wt (E, H, D) bf16
    transpose_f32_bf16<<<dim3(HH / 64, DD / 64, EE), 256, 0, stream>>>(
        W1 + (size_t)l * EE * DD * HH, Wt, DD, HH);
    gemm_kernel<DD, DD, HH, true><<<dim3(HH / 128, 68), 256, 0, stream>>>(
        h, Wt, b1 + l * EE * HH, (void*)a, meta);
    // W2 slice (E, H, D) fp32 -> Wt (E, D, H) bf16
    transpose_f32_bf16<<<dim3(DD / 64, HH / 64, EE), 256, 0, stream>>>(
        W2 + (size_t)l * EE * HH * DD, Wt, HH, DD);
    gemm_kernel<HH, HH / 2, DD, false><<<dim3(DD / 128, 68, 2), 256, 0, stream>>>(
        a, Wt, b2 + l * EE * DD, (void*)y, meta);
  }

  store_kernel<<<T_TOK / 4, 256, 0, stream>>>(xf, y, inv, (float*)d_out);
}